// Round 8
// baseline (271.983 us; speedup 1.0000x reference)
//
#include <hip/hip_runtime.h>

// N=4096, D=1024 self-attention, all GEMMs NT-form bf16 MFMA (16x16x32), fp32 acc.
// R4: BK=64 + XOR swizzle. R5: XCD swizzle. R7: softmax fused into epilogues.
// R12: V-transpose fused into k_qkv (MODE 3).
// R14 (REVERTED): BK=32 ring. R15 (REVERTED): split-K atomics.
// R16 (WIN, 213->207): k_score counted-vmcnt double-buffer (T3+T4+T5):
//   ds_read frags -> lgkm0 -> barrier -> stage(t+2, freed slot) -> MFMA
//   (setprio 1) -> vmcnt(N) -> barrier. Never vmcnt(0) mid-loop.
// R17 (WIN, 207->200): same pipeline on k_pv. R18 (WIN, 200->197.7): on k_qkv.
// R19/R20 (NEUTRAL, 197.7->196.8): k_score 8-phase 256x256 m201-style. Kept
//   (marginally best) but 8-phase != 2-phase here: K=1024 -> only 16 K-tiles,
//   1 blk/CU, exposed epilogue. All GEMMs at the ~700-780 TF 2-phase plateau.
// R21: k_qkv fused 3-slices -> 1 block computes Q,K,V 128x128 tiles sharing
//   ONE xb staging (A read 1x instead of 3x; staging bytes/K-unit 1.5x less;
//   48 MFMA per barrier-pair vs 32). BK=32 dbuf (2x32KB LDS), 8 loads/thr/
//   tile, vmcnt(8), chunk swizzle q = slot ^ (r&3) ^ ((r>>2)&3) (2-way worst,
//   free). acc 3x[4][4] f32x4 -> AGPRs (unified file). Grid (8,32)=256.
//
// ws layout:
//   Qb bf16[4096,1024] @ 0      Kb @ 8MB     Vt bf16[1024,4096] @ 24MB
//   SP bf16[4096,4096] @ 32MB   (exp'd scores; spans 32..64MB)
//   xb @ 32MB (overlaps SP; dead before k_score), Wqb @ 40MB, Wkb @ 42MB, Wvb @ 44MB
//   rowsum fp32[4096] @ 64MB    (past SP; ws_size >= 112MB proven in R3)

#define N_TOK 4096
#define DDIM  1024

typedef short s16x4 __attribute__((ext_vector_type(4)));
typedef short s16x8 __attribute__((ext_vector_type(8)));
typedef float f32x4 __attribute__((ext_vector_type(4)));

#define VMCNT0() asm volatile("s_waitcnt vmcnt(0)" ::: "memory")
#define VMCNT4() asm volatile("s_waitcnt vmcnt(4)" ::: "memory")
#define VMCNT6() asm volatile("s_waitcnt vmcnt(6)" ::: "memory")
#define VMCNT8() asm volatile("s_waitcnt vmcnt(8)" ::: "memory")
#define LGKMCNT0() asm volatile("s_waitcnt lgkmcnt(0)" ::: "memory")
#define SCHEDB() __builtin_amdgcn_sched_barrier(0)
#define BARRIER() do { asm volatile("" ::: "memory"); \
                       __builtin_amdgcn_s_barrier();  \
                       asm volatile("" ::: "memory"); } while (0)

__device__ inline short f2b(float f) {
  unsigned int u = __float_as_uint(f);
  unsigned int r = (u + 0x7FFFu + ((u >> 16) & 1u)) >> 16;
  return (short)(unsigned short)r;
}

__device__ __forceinline__ void gld_lds16(const short* g, short* l) {
  __builtin_amdgcn_global_load_lds(
      (const __attribute__((address_space(1))) unsigned int*)g,
      (__attribute__((address_space(3))) unsigned int*)l, 16, 0, 0);
}

// XCD-locality remap, GY=32 grids: XCD (L%8) owns a 4-row-tile band.
__device__ __forceinline__ void xcd_remap(int gx, int& bx, int& by) {
  const int L = by * gx + bx;
  const int g = L & 7, h = L >> 3;
  by = g * 4 + (h & 3);
  bx = h >> 2;
}
// 256-tile variant: XCD owns a 2-row-tile band.
__device__ __forceinline__ void xcd_remap16(int gx, int& bx, int& by) {
  const int L = by * gx + bx;
  const int g = L & 7, h = L >> 3;
  by = g * 2 + (h & 1);
  bx = h >> 1;
}

// ---------------------------------------------------------------------------
// fp32 -> bf16 conversion for x, Wq, Wk, Wv + rowsum zeroing (one launch).
// ---------------------------------------------------------------------------
#define XU  (N_TOK * DDIM / 8)      // 524288
#define WU  (DDIM * DDIM / 8)       // 131072
#define NCVT ((XU + 3 * WU) / 256)  // 3584 convert blocks
__global__ __launch_bounds__(256)
void cvt_all(const float* __restrict__ x,  const float* __restrict__ wq,
             const float* __restrict__ wk, const float* __restrict__ wv,
             short* __restrict__ xb, short* __restrict__ wqb,
             short* __restrict__ wkb, short* __restrict__ wvb,
             float* __restrict__ rowsum)
{
  if (blockIdx.x >= NCVT) {
    float4 z = {0.f, 0.f, 0.f, 0.f};
    float4* p = reinterpret_cast<float4*>(rowsum) + threadIdx.x * 4;
    p[0] = z; p[1] = z; p[2] = z; p[3] = z;
    return;
  }
  int gid = blockIdx.x * 256 + threadIdx.x;
  const float* src; short* dst; int off;
  if (gid < XU)               { src = x;  dst = xb;  off = gid; }
  else if (gid < XU + WU)     { src = wq; dst = wqb; off = gid - XU; }
  else if (gid < XU + 2 * WU) { src = wk; dst = wkb; off = gid - XU - WU; }
  else                        { src = wv; dst = wvb; off = gid - XU - 2 * WU; }
  const float4* g = reinterpret_cast<const float4*>(src) + (size_t)off * 2;
  float4 a = g[0], b = g[1];
  s16x8 o;
  o[0] = f2b(a.x); o[1] = f2b(a.y); o[2] = f2b(a.z); o[3] = f2b(a.w);
  o[4] = f2b(b.x); o[5] = f2b(b.y); o[6] = f2b(b.z); o[7] = f2b(b.w);
  reinterpret_cast<s16x8*>(dst)[off] = o;
}

// ---------------------------------------------------------------------------
// R21 k_qkv: fused Q/K/V GEMM. Each block owns (row0,col0) and computes all
// three 128x128 output tiles, staging xb ONCE per K-tile + 3 W tiles.
// BK=32, counted-vmcnt dbuf (R16 schedule): 2 x 32KB LDS, 8 loads/thr/tile,
// 48 MFMA/wave per barrier-pair, vmcnt(8). Grid (8,32) = 256 blocks.
// Slot layout (shorts): [A 128x32 | Wq 128x32 | Wk 128x32 | Wv 128x32].
// Chunk swizzle: chunk q of row r stored at slot q ^ (r&3) ^ ((r>>2)&3).
// ---------------------------------------------------------------------------
__global__ __launch_bounds__(256, 2)
void k_qkv(const short* __restrict__ xb,
           const short* __restrict__ Wqb, const short* __restrict__ Wkb,
           const short* __restrict__ Wvb,
           const float* __restrict__ bq, const float* __restrict__ bk,
           const float* __restrict__ bv,
           short* __restrict__ Qb, short* __restrict__ Kb, short* __restrict__ Vt)
{
  constexpr int BK = 32;
  constexpr int NT = DDIM / BK;                 // 32 K-tiles
  __shared__ short smem[2][4 * 128 * BK];       // 2 x 16384 shorts = 64 KiB

  int bx = blockIdx.x, by = blockIdx.y;
  xcd_remap(8, bx, by);
  const int row0 = by * 128, col0 = bx * 128;

  const int tid  = threadIdx.x;
  const int wave = tid >> 6, lane = tid & 63;
  const int wm = wave >> 1, wn = wave & 1;      // 2x2 waves, 64x64 per output
  const int quad = lane >> 4, lr = lane & 15;

  auto stage = [&](int t, int sl) {
    #pragma unroll
    for (int c = 0; c < 8; c++) {
      const int id = c * 256 + tid;             // 0..2047
      const int r  = id >> 2;                   // 0..511 (A | Wq | Wk | Wv)
      const int q  = (id & 3) ^ (r & 3) ^ ((r >> 2) & 3);
      const int rr = r & 127;
      const short* src =
          (r < 128) ? xb  + (size_t)(row0 + rr) * DDIM + t * BK + q * 8 :
          (r < 256) ? Wqb + (size_t)(col0 + rr) * DDIM + t * BK + q * 8 :
          (r < 384) ? Wkb + (size_t)(col0 + rr) * DDIM + t * BK + q * 8 :
                      Wvb + (size_t)(col0 + rr) * DDIM + t * BK + q * 8;
      gld_lds16(src, &smem[sl][(c * 256 + wave * 64) * 8]);
    }
  };

  f32x4 aq[4][4], ak[4][4], av[4][4];
  #pragma unroll
  for (int i = 0; i < 4; i++)
    #pragma unroll
    for (int j = 0; j < 4; j++) {
      aq[i][j] = {0.f, 0.f, 0.f, 0.f};
      ak[i][j] = {0.f, 0.f, 0.f, 0.f};
      av[i][j] = {0.f, 0.f, 0.f, 0.f};
    }

  stage(0, 0);
  stage(1, 1);
  VMCNT8();
  BARRIER();

  for (int t = 0; t < NT; t++) {
    const int sl = t & 1;
    const short* As = smem[sl];
    const short* Bq = smem[sl] + 4096;
    const short* Bk = smem[sl] + 8192;
    const short* Bv = smem[sl] + 12288;

    s16x8 af[4], fq[4], fk[4], fv[4];
    #pragma unroll
    for (int i = 0; i < 4; i++) {
      const int row = wm * 64 + i * 16 + lr;
      const int ch = quad ^ (row & 3) ^ ((row >> 2) & 3);
      af[i] = *reinterpret_cast<const s16x8*>(&As[(row * 4 + ch) * 8]);
    }
    #pragma unroll
    for (int j = 0; j < 4; j++) {
      const int row = wn * 64 + j * 16 + lr;
      const int ch = quad ^ (row & 3) ^ ((row >> 2) & 3);
      fq[j] = *reinterpret_cast<const s16x8*>(&Bq[(row * 4 + ch) * 8]);
      fk[j] = *reinterpret_cast<const s16x8*>(&Bk[(row * 4 + ch) * 8]);
      fv[j] = *reinterpret_cast<const s16x8*>(&Bv[(row * 4 + ch) * 8]);
    }
    LGKMCNT0();
    SCHEDB();
    BARRIER();                                   // slot sl reusable block-wide

    const bool pf = (t + 2) < NT;
    if (pf) stage(t + 2, sl);

    __builtin_amdgcn_s_setprio(1);
    #pragma unroll
    for (int i = 0; i < 4; i++)
      #pragma unroll
      for (int j = 0; j < 4; j++) {
        aq[i][j] = __builtin_amdgcn_mfma_f32_16x16x32_bf16(af[i], fq[j], aq[i][j], 0, 0, 0);
        ak[i][j] = __builtin_amdgcn_mfma_f32_16x16x32_bf16(af[i], fk[j], ak[i][j], 0, 0, 0);
        av[i][j] = __builtin_amdgcn_mfma_f32_16x16x32_bf16(af[i], fv[j], av[i][j], 0, 0, 0);
      }
    __builtin_amdgcn_s_setprio(0);

    if (pf) { VMCNT8(); } else { VMCNT0(); }
    BARRIER();
  }
  // loop exit: tail vmcnt(0)+barrier drained -> smem reusable.

  // Q and K epilogues: bf16 store of acc + bias (coalesced rows).
  {
    float bbq[4], bbk[4];
    #pragma unroll
    for (int j = 0; j < 4; j++) {
      bbq[j] = bq[col0 + wn * 64 + j * 16 + lr];
      bbk[j] = bk[col0 + wn * 64 + j * 16 + lr];
    }
    #pragma unroll
    for (int i = 0; i < 4; i++) {
      const int r0 = row0 + wm * 64 + i * 16 + quad * 4;
      #pragma unroll
      for (int j = 0; j < 4; j++) {
        const int c = col0 + wn * 64 + j * 16 + lr;
        #pragma unroll
        for (int r = 0; r < 4; r++) {
          Qb[(size_t)(r0 + r) * DDIM + c] = f2b(aq[i][j][r] + bbq[j]);
          Kb[(size_t)(r0 + r) * DDIM + c] = f2b(ak[i][j][r] + bbk[j]);
        }
      }
    }
  }

  // V epilogue: transposed bf16 store via LDS trans buffer (stride 136).
  {
    float bbv[4];
    #pragma unroll
    for (int j = 0; j < 4; j++) bbv[j] = bv[col0 + wn * 64 + j * 16 + lr];
    short* trans = &smem[0][0];                  // 128 x 136 shorts
    #pragma unroll
    for (int i = 0; i < 4; i++) {
      const int rl = wm * 64 + i * 16 + quad * 4;
      #pragma unroll
      for (int j = 0; j < 4; j++) {
        const int cl = wn * 64 + j * 16 + lr;
        s16x4 v;
        #pragma unroll
        for (int r = 0; r < 4; r++) v[r] = f2b(av[i][j][r] + bbv[j]);
        *reinterpret_cast<s16x4*>(&trans[cl * 136 + rl]) = v;
      }
    }
    BARRIER();
    #pragma unroll
    for (int s = 0; s < 8; s++) {
      const int u = s * 256 + tid;
      const int cc = u >> 4;                     // column 0..127
      const int seg = u & 15;                    // 16 segs x 8 shorts
      s16x8 v = *reinterpret_cast<const s16x8*>(&trans[cc * 136 + seg * 8]);
      *reinterpret_cast<s16x8*>(
          &Vt[(size_t)(col0 + cc) * N_TOK + row0 + seg * 8]) = v;
    }
  }
}

// ---------------------------------------------------------------------------
// R19/R20 k_score: 8-phase 256x256 BK=64 schedule (m201-style), 512 threads.
// 8 waves (2M x 4N), per-wave C = 128x64 (acc[8][4]). LDS 2 x 64KB = 128KB.
// vmcnt(4) only at phases 3/7; never vmcnt(0) mid-loop.
// ---------------------------------------------------------------------------
#define READ_AF(As, MH) do {                                                  \
    _Pragma("unroll")                                                         \
    for (int kh = 0; kh < 2; kh++)                                            \
      _Pragma("unroll")                                                       \
      for (int f = 0; f < 4; f++) {                                           \
        const int row_ = wm * 128 + (MH) * 64 + f * 16 + lr;                  \
        const int ch_ = (kh * 4 + quad) ^ (row_ & 7);                         \
        af[kh][f] = *reinterpret_cast<const s16x8*>(&(As)[(row_ * 8 + ch_) * 8]); \
      }                                                                       \
  } while (0)

#define READ_BF(Bs, NH, BF) do {                                              \
    _Pragma("unroll")                                                         \
    for (int kh = 0; kh < 2; kh++)                                            \
      _Pragma("unroll")                                                       \
      for (int g = 0; g < 2; g++) {                                           \
        const int row_ = wn * 64 + (NH) * 32 + g * 16 + lr;                   \
        const int ch_ = (kh * 4 + quad) ^ (row_ & 7);                         \
        BF[kh][g] = *reinterpret_cast<const s16x8*>(&(Bs)[(row_ * 8 + ch_) * 8]); \
      }                                                                       \
  } while (0)

#define MFMA_Q(MH, NH, BF) do {                                               \
    __builtin_amdgcn_s_setprio(1);                                            \
    _Pragma("unroll")                                                         \
    for (int kh = 0; kh < 2; kh++)                                            \
      _Pragma("unroll")                                                       \
      for (int f = 0; f < 4; f++)                                             \
        _Pragma("unroll")                                                     \
        for (int g = 0; g < 2; g++)                                           \
          acc[(MH) * 4 + f][(NH) * 2 + g] =                                   \
              __builtin_amdgcn_mfma_f32_16x16x32_bf16(                        \
                  af[kh][f], BF[kh][g], acc[(MH) * 4 + f][(NH) * 2 + g],      \
                  0, 0, 0);                                                   \
    __builtin_amdgcn_s_setprio(0);                                            \
  } while (0)

__global__ __launch_bounds__(512, 2)
void k_score(const short* __restrict__ Qb, const short* __restrict__ Kb,
             short* __restrict__ SP, float* __restrict__ rowsum)
{
  constexpr int NITER = 8;                      // 16 K-tiles, 2 per iter
  __shared__ short smem[2][32768];              // [buf][A 256x64 | B 256x64] 128KB

  int bx = blockIdx.x, by = blockIdx.y;
  xcd_remap16(16, bx, by);
  const int row0 = by * 256, col0 = bx * 256;

  const int tid  = threadIdx.x;
  const int wave = tid >> 6, lane = tid & 63;
  const int wm = wave >> 2, wn = wave & 3;      // 2x4 waves, 128x64 of C each
  const int quad = lane >> 4, lr = lane & 15;

  auto stage_h = [&](int t, int b, int h) {
    const short* gbase = (h < 2)
        ? Qb + (size_t)(row0 + (h & 1) * 128) * DDIM
        : Kb + (size_t)(col0 + (h & 1) * 128) * DDIM;
    short* dst = &smem[b][(h >> 1) * 16384 + (h & 1) * 8192];
    #pragma unroll
    for (int c = 0; c < 2; c++) {
      const int id = c * 512 + tid;             // 0..1023
      const int r  = id >> 3;                   // 0..127
      const int q  = (id & 7) ^ (r & 7);
      gld_lds16(gbase + (size_t)r * DDIM + t * 64 + q * 8,
                dst + (c * 512 + wave * 64) * 8);
    }
  };

  s16x8 af[2][4], bf0[2][2], bf1[2][2];
  f32x4 acc[8][4];
  #pragma unroll
  for (int i = 0; i < 8; i++)
    #pragma unroll
    for (int j = 0; j < 4; j++) acc[i][j] = {0.f, 0.f, 0.f, 0.f};

  const short* As0 = smem[0];
  const short* Bs0 = smem[0] + 16384;
  const short* As1 = smem[1];
  const short* Bs1 = smem[1] + 16384;

  stage_h(0, 0, 2); stage_h(0, 0, 3); stage_h(0, 0, 0); stage_h(0, 0, 1);
  stage_h(1, 1, 2); stage_h(1, 1, 0);
  VMCNT4();
  BARRIER();

  for (int i = 0; i < NITER; i++) {
    const int t1 = 2 * i + 1;
    const bool more = (i + 1) < NITER;

    READ_AF(As0, 0); READ_BF(Bs0, 0, bf0);
    stage_h(t1, 1, 3);
    BARRIER(); LGKMCNT0(); SCHEDB();
    MFMA_Q(0, 0, bf0);
    BARRIER();
    READ_BF(Bs0, 1, bf1);
    stage_h(t1, 1, 1);
    BARRIER(); LGKMCNT0(); SCHEDB();
    MFMA_Q(0, 1, bf1);
    BARRIER();
    READ_AF(As0, 1);
    if (more) stage_h(t1 + 1, 0, 2);
    BARRIER(); LGKMCNT0(); SCHEDB();
    MFMA_Q(1, 1, bf1);
    BARRIER();
    if (more) { stage_h(t1 + 1, 0, 0); VMCNT4(); } else { VMCNT0(); }
    BARRIER();
    MFMA_Q(1, 0, bf0);
    BARRIER();
    READ_AF(As1, 0); READ_BF(Bs1, 0, bf0);
    if (more) stage_h(t1 + 1, 0, 3);
    BARRIER(); LGKMCNT0(); SCHEDB();
    MFMA_Q(0, 0, bf0);
    BARRIER();
    READ_BF(Bs1, 1, bf1);
    if (more) stage_h(t1 + 1, 0, 1);
    BARRIER(); LGKMCNT0(); SCHEDB();
    MFMA_Q(0, 1, bf1);
    BARRIER();
    READ_AF(As1, 1);
    if (more) stage_h(t1 + 2, 1, 2);
    BARRIER(); LGKMCNT0(); SCHEDB();
    MFMA_Q(1, 1, bf1);
    BARRIER();
    if (more) { stage_h(t1 + 2, 1, 0); VMCNT4(); } else { VMCNT0(); }
    BARRIER();
    MFMA_Q(1, 0, bf0);
    BARRIER();
  }

  constexpr float scale = 0.03125f;
  #pragma unroll
  for (int i = 0; i < 8; i++) {
    const int r0 = row0 + wm * 128 + i * 16 + quad * 4;
    float ex[4][4];
    #pragma unroll
    for (int j = 0; j < 4; j++) {
      const int c = col0 + wn * 64 + j * 16 + lr;
      #pragma unroll
      for (int r = 0; r < 4; r++) {
        ex[j][r] = __expf(acc[i][j][r] * scale);
        SP[(size_t)(r0 + r) * N_TOK + c] = f2b(ex[j][r]);
      }
    }
    #pragma unroll
    for (int r = 0; r < 4; r++) {
      float s = 0.f;
      #pragma unroll
      for (int j = 0; j < 4; j++) s += ex[j][r];
      s += __shfl_xor(s, 1, 64);
      s += __shfl_xor(s, 2, 64);
      s += __shfl_xor(s, 4, 64);
      s += __shfl_xor(s, 8, 64);
      if (lr == 0) atomicAdd(&rowsum[r0 + r], s);
    }
  }
}

// ---------------------------------------------------------------------------
// R17 k_pv: 128x64 tile, BK=64, counted-vmcnt double-buffer (R16 schedule).
// Grid (16,32)=512 = 2 blk/CU; LDS 2 x 24KB = 48KB; 6 loads/thr/tile, vmcnt(6).
// ---------------------------------------------------------------------------
__global__ __launch_bounds__(256, 2)
void k_pv(const short* __restrict__ SP, const short* __restrict__ Vt,
          float* __restrict__ out, const float* __restrict__ rowsum)
{
  constexpr int BM = 128, BN = 64, BK = 64;
  constexpr int NT = N_TOK / BK;                // 64 K-tiles
  __shared__ short smem[2][(BM + BN) * BK];     // 2 x 12288 shorts = 48 KiB

  int bx = blockIdx.x, by = blockIdx.y;
  xcd_remap(DDIM / 64, bx, by);
  const int row0 = by * BM, col0 = bx * BN;

  const int tid  = threadIdx.x;
  const int wave = tid >> 6, lane = tid & 63;
  const int wm = wave >> 1, wn = wave & 1;      // 2x2 waves, 64x32 out each
  const int quad = lane >> 4, lr = lane & 15;

  auto stage = [&](int t, int sl) {
    #pragma unroll
    for (int c = 0; c < 6; c++) {
      const int id = c * 256 + tid;             // 0..1535
      const int r  = id >> 3;                   // rows 0..191 (A:0-127, B:128-191)
      const int q  = (id & 7) ^ (r & 7);
      const short* src = (r < BM)
          ? SP + (size_t)(row0 + r) * N_TOK + t * BK + q * 8
          : Vt + (size_t)(col0 + r - BM) * N_TOK + t * BK + q * 8;
      gld_lds16(src, &smem[sl][(c * 256 + wave * 64) * 8]);
    }
  };

  f32x4 acc[4][2];
  #pragma unroll
  for (int i = 0; i < 4; i++)
    #pragma unroll
    for (int j = 0; j < 2; j++) acc[i][j] = {0.f, 0.f, 0.f, 0.f};

  stage(0, 0);
  stage(1, 1);
  VMCNT6();
  BARRIER();

  for (int t = 0; t < NT; t++) {
    const int sl = t & 1;
    const short* As = smem[sl];
    const short* Bs = smem[sl] + BM * BK;

    s16x8 af[2][4], bf[2][2];
    #pragma unroll
    for (int h = 0; h < 2; h++) {
      #pragma unroll
      for (int i = 0; i < 4; i++) {
        const int row = wm * 64 + i * 16 + lr;
        const int ch = (h * 4 + quad) ^ (row & 7);
        af[h][i] = *reinterpret_cast<const s16x8*>(&As[(row * 8 + ch) * 8]);
      }
      #pragma unroll
      for (int j = 0; j < 2; j++) {
        const int row = wn * 32 + j * 16 + lr;
        const int ch = (h * 4 + quad) ^ (row & 7);
        bf[h][j] = *reinterpret_cast<const s16x8*>(&Bs[(row * 8 + ch) * 8]);
      }
    }
    LGKMCNT0();
    SCHEDB();
    BARRIER();                                   // slot sl reusable block-wide

    const bool pf = (t + 2) < NT;
    if (pf) stage(t + 2, sl);

    __builtin_amdgcn_s_setprio(1);
    #pragma unroll
    for (int h = 0; h < 2; h++)
      #pragma unroll
      for (int i = 0; i < 4; i++)
        #pragma unroll
        for (int j = 0; j < 2; j++)
          acc[i][j] = __builtin_amdgcn_mfma_f32_16x16x32_bf16(
              af[h][i], bf[h][j], acc[i][j], 0, 0, 0);
    __builtin_amdgcn_s_setprio(0);

    if (pf) { VMCNT6(); } else { VMCNT0(); }
    BARRIER();
  }

  // epilogue: O = acc / rowsum[row], fp32 coalesced store
  #pragma unroll
  for (int i = 0; i < 4; i++) {
    const int r0 = row0 + wm * 64 + i * 16 + quad * 4;
    float linv[4];
    #pragma unroll
    for (int r = 0; r < 4; r++) linv[r] = 1.0f / rowsum[r0 + r];
    #pragma unroll
    for (int j = 0; j < 2; j++) {
      const int c = col0 + wn * 32 + j * 16 + lr;
      #pragma unroll
      for (int r = 0; r < 4; r++)
        out[(size_t)(r0 + r) * DDIM + c] = acc[i][j][r] * linv[r];
    }
  }
}

// ---------------------------------------------------------------------------
extern "C" void kernel_launch(void* const* d_in, const int* in_sizes, int n_in,
                              void* d_out, int out_size, void* d_ws, size_t ws_size,
                              hipStream_t stream)
{
  const float* x  = (const float*)d_in[0];
  const float* Wq = (const float*)d_in[1];
  const float* bq = (const float*)d_in[2];
  const float* Wk = (const float*)d_in[3];
  const float* bk = (const float*)d_in[4];
  const float* Wv = (const float*)d_in[5];
  const float* bv = (const float*)d_in[6];
  float* out = (float*)d_out;

  char* ws = (char*)d_ws;
  const size_t MB = 1024 * 1024;
  short* Qb  = (short*)(ws + 0 * MB);
  short* Kb  = (short*)(ws + 8 * MB);
  short* Vt  = (short*)(ws + 24 * MB);
  short* SP  = (short*)(ws + 32 * MB);   // 32 MB (32..64MB)
  short* xb  = (short*)(ws + 32 * MB);   // overlaps SP (dead before k_score)
  short* Wqb = (short*)(ws + 40 * MB);
  short* Wkb = (short*)(ws + 42 * MB);
  short* Wvb = (short*)(ws + 44 * MB);
  float* rowsum = (float*)(ws + 64 * MB); // past SP (ws >= 112MB, proven R3)

  dim3 b256(256);

  // fp32 -> bf16 for x and the three W's + zero rowsum (one extra block)
  cvt_all<<<dim3(NCVT + 1), b256, 0, stream>>>(
      x, Wq, Wk, Wv, xb, Wqb, Wkb, Wvb, rowsum);

  // Q/K/V fused: one block computes all three 128x128 tiles, xb staged once
  k_qkv<<<dim3(8, 32), b256, 0, stream>>>(
      xb, Wqb, Wkb, Wvb, bq, bk, bv, Qb, Kb, Vt);

  // P = exp(Q @ K^T / 32) (bf16) + rowsum atomics; 8-phase 256x256 schedule
  k_score<<<dim3(16, 16), dim3(512), 0, stream>>>(Qb, Kb, SP, rowsum);

  // O = (P @ Vt^T) / rowsum (fp32 out), dbuf-pipelined 128x64 BK=64
  k_pv<<<dim3(DDIM / 64, N_TOK / 128), b256, 0, stream>>>(
      SP, Vt, out, rowsum);
}

// Round 9
// 194.526 us; speedup vs baseline: 1.3982x; 1.3982x over previous
//
#include <hip/hip_runtime.h>

// N=4096, D=1024 self-attention, all GEMMs NT-form bf16 MFMA (16x16x32), fp32 acc.
// R4: BK=64 + XOR swizzle. R5: XCD swizzle. R7: softmax fused into epilogues.
// R12: V-transpose fused into k_qkv (MODE 3).
// R14 (REVERTED): BK=32 ring. R15 (REVERTED): split-K atomics.
// R16 (WIN, 213->207): k_score counted-vmcnt double-buffer (T3+T4+T5).
// R17 (WIN, 207->200): same on k_pv. R18 (WIN, 200->197.7): on k_qkv.
// R19/R20 (NEUTRAL, ->196.8): k_score 8-phase 256x256. Kept (marginal best).
// R21 (REVERTED, 272): fused-QKV blew registers (192 acc) + BK=32 row-stride
//   bank conflicts (2.2M). RULE: the chunk-XOR swizzle needs BK=64 row stride.
// R22: revert k_qkv to R18 3-slice + replace rowsum atomics with partials:
//   k_score epilogue does wave-shfl -> LDS wn-reduce -> non-atomic store to
//   rowsum_p[16][4096] (bx-owned stripe, each element written once, no
//   zeroing); k_pv sums 16 partials via float4 loads. Removes 524K contended
//   fp32 atomicAdds (128 RMWs/address, serialized per line).
//
// ws layout:
//   Qb bf16[4096,1024] @ 0      Kb @ 8MB     Vt bf16[1024,4096] @ 24MB
//   SP bf16[4096,4096] @ 32MB   (exp'd scores; spans 32..64MB)
//   xb @ 32MB (overlaps SP; dead before k_score), Wqb @ 40MB, Wkb @ 42MB, Wvb @ 44MB
//   rowsum_p fp32[16][4096] @ 64MB (past SP; ws >= 112MB proven in R3)

#define N_TOK 4096
#define DDIM  1024

typedef short s16x4 __attribute__((ext_vector_type(4)));
typedef short s16x8 __attribute__((ext_vector_type(8)));
typedef float f32x4 __attribute__((ext_vector_type(4)));

#define VMCNT0() asm volatile("s_waitcnt vmcnt(0)" ::: "memory")
#define VMCNT4() asm volatile("s_waitcnt vmcnt(4)" ::: "memory")
#define VMCNT6() asm volatile("s_waitcnt vmcnt(6)" ::: "memory")
#define VMCNT8() asm volatile("s_waitcnt vmcnt(8)" ::: "memory")
#define LGKMCNT0() asm volatile("s_waitcnt lgkmcnt(0)" ::: "memory")
#define SCHEDB() __builtin_amdgcn_sched_barrier(0)
#define BARRIER() do { asm volatile("" ::: "memory"); \
                       __builtin_amdgcn_s_barrier();  \
                       asm volatile("" ::: "memory"); } while (0)

__device__ inline short f2b(float f) {
  unsigned int u = __float_as_uint(f);
  unsigned int r = (u + 0x7FFFu + ((u >> 16) & 1u)) >> 16;
  return (short)(unsigned short)r;
}

__device__ __forceinline__ void gld_lds16(const short* g, short* l) {
  __builtin_amdgcn_global_load_lds(
      (const __attribute__((address_space(1))) unsigned int*)g,
      (__attribute__((address_space(3))) unsigned int*)l, 16, 0, 0);
}

// XCD-locality remap, GY=32 grids: XCD (L%8) owns a 4-row-tile band.
__device__ __forceinline__ void xcd_remap(int gx, int& bx, int& by) {
  const int L = by * gx + bx;
  const int g = L & 7, h = L >> 3;
  by = g * 4 + (h & 3);
  bx = h >> 2;
}
// 256-tile variant: XCD owns a 2-row-tile band.
__device__ __forceinline__ void xcd_remap16(int gx, int& bx, int& by) {
  const int L = by * gx + bx;
  const int g = L & 7, h = L >> 3;
  by = g * 2 + (h & 1);
  bx = h >> 1;
}

// ---------------------------------------------------------------------------
// R18 pipelined 128x128 BK=64 NT GEMM (R16 schedule). MODE epilogues:
//   0: bf16 store of scale*acc + bias                  (aux = bias)
//   3: bf16 TRANSPOSED store of acc + bias             (aux = bias)
// smem: 2 slots x 16384 shorts (64 KiB). ldA == ldB == ld.
// ---------------------------------------------------------------------------
template<int MODE>
__device__ __forceinline__ void gemm_pipe128(
    const short* __restrict__ A, const short* __restrict__ B,
    void* __restrict__ C, const float* __restrict__ aux,
    short (*smem)[(128 + 128) * 64],
    int K, int ld, int ldc, float scale, int row0, int col0)
{
  constexpr int BM = 128, BN = 128, BK = 64;
  const int NT = K / BK;

  const int tid  = threadIdx.x;
  const int wave = tid >> 6, lane = tid & 63;
  const int wm = wave >> 1, wn = wave & 1;      // 2x2 waves, 64x64 out each
  const int quad = lane >> 4, lr = lane & 15;

  auto stage = [&](int t, int sl) {
    #pragma unroll
    for (int c = 0; c < 8; c++) {
      const int id = c * 256 + tid;             // 0..2047
      const int r  = id >> 3;                   // rows 0..255 (A:0-127, B:128-255)
      const int q  = (id & 7) ^ (r & 7);
      const short* src = (r < BM)
          ? A + (size_t)(row0 + r) * ld + t * BK + q * 8
          : B + (size_t)(col0 + r - BM) * ld + t * BK + q * 8;
      gld_lds16(src, &smem[sl][(c * 256 + wave * 64) * 8]);
    }
  };

  f32x4 acc[4][4];
  #pragma unroll
  for (int i = 0; i < 4; i++)
    #pragma unroll
    for (int j = 0; j < 4; j++) acc[i][j] = {0.f, 0.f, 0.f, 0.f};

  stage(0, 0);
  stage(1, 1);
  VMCNT8();
  BARRIER();

  for (int t = 0; t < NT; t++) {
    const int sl = t & 1;
    const short* As = smem[sl];
    const short* Bs = smem[sl] + BM * BK;

    s16x8 af[2][4], bf[2][4];
    #pragma unroll
    for (int h = 0; h < 2; h++) {
      #pragma unroll
      for (int i = 0; i < 4; i++) {
        const int row = wm * 64 + i * 16 + lr;
        const int ch = (h * 4 + quad) ^ (row & 7);
        af[h][i] = *reinterpret_cast<const s16x8*>(&As[(row * 8 + ch) * 8]);
      }
      #pragma unroll
      for (int j = 0; j < 4; j++) {
        const int row = wn * 64 + j * 16 + lr;
        const int ch = (h * 4 + quad) ^ (row & 7);
        bf[h][j] = *reinterpret_cast<const s16x8*>(&Bs[(row * 8 + ch) * 8]);
      }
    }
    LGKMCNT0();
    SCHEDB();
    BARRIER();                                   // slot sl reusable block-wide

    const bool pf = (t + 2) < NT;
    if (pf) stage(t + 2, sl);

    __builtin_amdgcn_s_setprio(1);
    #pragma unroll
    for (int h = 0; h < 2; h++)
      #pragma unroll
      for (int i = 0; i < 4; i++)
        #pragma unroll
        for (int j = 0; j < 4; j++)
          acc[i][j] = __builtin_amdgcn_mfma_f32_16x16x32_bf16(
              af[h][i], bf[h][j], acc[i][j], 0, 0, 0);
    __builtin_amdgcn_s_setprio(0);

    if (pf) { VMCNT8(); } else { VMCNT0(); }
    BARRIER();
  }
  // loop exit: all LDS reads drained (tail vmcnt(0)+barrier) -> smem reusable.

  if constexpr (MODE == 0) {
    float bb[4];
    #pragma unroll
    for (int j = 0; j < 4; j++) bb[j] = aux[col0 + wn * 64 + j * 16 + lr];
    #pragma unroll
    for (int i = 0; i < 4; i++) {
      const int r0 = row0 + wm * 64 + i * 16 + quad * 4;
      #pragma unroll
      for (int j = 0; j < 4; j++) {
        const int c = col0 + wn * 64 + j * 16 + lr;
        #pragma unroll
        for (int r = 0; r < 4; r++)
          ((short*)C)[(size_t)(r0 + r) * ldc + c] = f2b(acc[i][j][r] * scale + bb[j]);
      }
    }
  } else {
    // MODE 3: transposed bf16 store with bias. trans[col][row], stride 136.
    float bb[4];
    #pragma unroll
    for (int j = 0; j < 4; j++) bb[j] = aux[col0 + wn * 64 + j * 16 + lr];
    short* trans = &smem[0][0];                  // 128 x 136 shorts = 34816 B
    #pragma unroll
    for (int i = 0; i < 4; i++) {
      const int rl = wm * 64 + i * 16 + quad * 4;
      #pragma unroll
      for (int j = 0; j < 4; j++) {
        const int cl = wn * 64 + j * 16 + lr;
        s16x4 v;
        #pragma unroll
        for (int r = 0; r < 4; r++) v[r] = f2b(acc[i][j][r] * scale + bb[j]);
        *reinterpret_cast<s16x4*>(&trans[cl * 136 + rl]) = v;
      }
    }
    BARRIER();
    #pragma unroll
    for (int s = 0; s < 8; s++) {
      const int u = s * 256 + tid;
      const int cc = u >> 4;                     // column 0..127
      const int seg = u & 15;                    // 16 segs x 8 shorts = 128 rows
      s16x8 v = *reinterpret_cast<const s16x8*>(&trans[cc * 136 + seg * 8]);
      *reinterpret_cast<s16x8*>(
          &((short*)C)[(size_t)(col0 + cc) * ldc + row0 + seg * 8]) = v;
    }
  }
}

// ---------------------------------------------------------------------------
// fp32 -> bf16 conversion for x, Wq, Wk, Wv (one launch; no zeroing needed --
// rowsum_p is written non-atomically with full coverage).
// ---------------------------------------------------------------------------
#define XU  (N_TOK * DDIM / 8)      // 524288
#define WU  (DDIM * DDIM / 8)       // 131072
#define NCVT ((XU + 3 * WU) / 256)  // 3584 convert blocks
__global__ __launch_bounds__(256)
void cvt_all(const float* __restrict__ x,  const float* __restrict__ wq,
             const float* __restrict__ wk, const float* __restrict__ wv,
             short* __restrict__ xb, short* __restrict__ wqb,
             short* __restrict__ wkb, short* __restrict__ wvb)
{
  int gid = blockIdx.x * 256 + threadIdx.x;
  const float* src; short* dst; int off;
  if (gid < XU)               { src = x;  dst = xb;  off = gid; }
  else if (gid < XU + WU)     { src = wq; dst = wqb; off = gid - XU; }
  else if (gid < XU + 2 * WU) { src = wk; dst = wkb; off = gid - XU - WU; }
  else                        { src = wv; dst = wvb; off = gid - XU - 2 * WU; }
  const float4* g = reinterpret_cast<const float4*>(src) + (size_t)off * 2;
  float4 a = g[0], b = g[1];
  s16x8 o;
  o[0] = f2b(a.x); o[1] = f2b(a.y); o[2] = f2b(a.z); o[3] = f2b(a.w);
  o[4] = f2b(b.x); o[5] = f2b(b.y); o[6] = f2b(b.z); o[7] = f2b(b.w);
  reinterpret_cast<s16x8*>(dst)[off] = o;
}

// ---------------------------------------------------------------------------
// R18 k_qkv: pipelined 128x128 BK=64; grid (8,32,3); LDS 64KB -> 2 blk/CU.
// ---------------------------------------------------------------------------
__global__ __launch_bounds__(256, 2)
void k_qkv(const short* __restrict__ xb,
           const short* __restrict__ Wqb, const short* __restrict__ Wkb,
           const short* __restrict__ Wvb,
           const float* __restrict__ bq, const float* __restrict__ bk,
           const float* __restrict__ bv,
           short* __restrict__ Qb, short* __restrict__ Kb, short* __restrict__ Vt)
{
  __shared__ short smem[2][(128 + 128) * 64];   // 64 KiB
  int bx = blockIdx.x, by = blockIdx.y;
  xcd_remap(DDIM / 128, bx, by);
  if (blockIdx.z == 0) {
    gemm_pipe128<0>(xb, Wqb, Qb, bq, smem, DDIM, DDIM, DDIM,
                    1.0f, by * 128, bx * 128);
  } else if (blockIdx.z == 1) {
    gemm_pipe128<0>(xb, Wkb, Kb, bk, smem, DDIM, DDIM, DDIM,
                    1.0f, by * 128, bx * 128);
  } else {
    gemm_pipe128<3>(xb, Wvb, Vt, bv, smem, DDIM, DDIM, N_TOK,
                    1.0f, by * 128, bx * 128);
  }
}

// ---------------------------------------------------------------------------
// R19/R20 k_score: 8-phase 256x256 BK=64 schedule, 512 threads, 128KB LDS.
// R22 epilogue: rowsum partials (LDS wn-reduce + non-atomic store), no atomics.
// ---------------------------------------------------------------------------
#define READ_AF(As, MH) do {                                                  \
    _Pragma("unroll")                                                         \
    for (int kh = 0; kh < 2; kh++)                                            \
      _Pragma("unroll")                                                       \
      for (int f = 0; f < 4; f++) {                                           \
        const int row_ = wm * 128 + (MH) * 64 + f * 16 + lr;                  \
        const int ch_ = (kh * 4 + quad) ^ (row_ & 7);                         \
        af[kh][f] = *reinterpret_cast<const s16x8*>(&(As)[(row_ * 8 + ch_) * 8]); \
      }                                                                       \
  } while (0)

#define READ_BF(Bs, NH, BF) do {                                              \
    _Pragma("unroll")                                                         \
    for (int kh = 0; kh < 2; kh++)                                            \
      _Pragma("unroll")                                                       \
      for (int g = 0; g < 2; g++) {                                           \
        const int row_ = wn * 64 + (NH) * 32 + g * 16 + lr;                   \
        const int ch_ = (kh * 4 + quad) ^ (row_ & 7);                         \
        BF[kh][g] = *reinterpret_cast<const s16x8*>(&(Bs)[(row_ * 8 + ch_) * 8]); \
      }                                                                       \
  } while (0)

#define MFMA_Q(MH, NH, BF) do {                                               \
    __builtin_amdgcn_s_setprio(1);                                            \
    _Pragma("unroll")                                                         \
    for (int kh = 0; kh < 2; kh++)                                            \
      _Pragma("unroll")                                                       \
      for (int f = 0; f < 4; f++)                                             \
        _Pragma("unroll")                                                     \
        for (int g = 0; g < 2; g++)                                           \
          acc[(MH) * 4 + f][(NH) * 2 + g] =                                   \
              __builtin_amdgcn_mfma_f32_16x16x32_bf16(                        \
                  af[kh][f], BF[kh][g], acc[(MH) * 4 + f][(NH) * 2 + g],      \
                  0, 0, 0);                                                   \
    __builtin_amdgcn_s_setprio(0);                                            \
  } while (0)

__global__ __launch_bounds__(512, 2)
void k_score(const short* __restrict__ Qb, const short* __restrict__ Kb,
             short* __restrict__ SP, float* __restrict__ rowsum_p)
{
  constexpr int NITER = 8;                      // 16 K-tiles, 2 per iter
  __shared__ short smem[2][32768];              // [buf][A 256x64 | B 256x64] 128KB

  int bx = blockIdx.x, by = blockIdx.y;
  xcd_remap16(16, bx, by);
  const int row0 = by * 256, col0 = bx * 256;

  const int tid  = threadIdx.x;
  const int wave = tid >> 6, lane = tid & 63;
  const int wm = wave >> 2, wn = wave & 3;      // 2x4 waves, 128x64 of C each
  const int quad = lane >> 4, lr = lane & 15;

  auto stage_h = [&](int t, int b, int h) {
    const short* gbase = (h < 2)
        ? Qb + (size_t)(row0 + (h & 1) * 128) * DDIM
        : Kb + (size_t)(col0 + (h & 1) * 128) * DDIM;
    short* dst = &smem[b][(h >> 1) * 16384 + (h & 1) * 8192];
    #pragma unroll
    for (int c = 0; c < 2; c++) {
      const int id = c * 512 + tid;             // 0..1023
      const int r  = id >> 3;                   // 0..127
      const int q  = (id & 7) ^ (r & 7);
      gld_lds16(gbase + (size_t)r * DDIM + t * 64 + q * 8,
                dst + (c * 512 + wave * 64) * 8);
    }
  };

  s16x8 af[2][4], bf0[2][2], bf1[2][2];
  f32x4 acc[8][4];
  #pragma unroll
  for (int i = 0; i < 8; i++)
    #pragma unroll
    for (int j = 0; j < 4; j++) acc[i][j] = {0.f, 0.f, 0.f, 0.f};

  const short* As0 = smem[0];
  const short* Bs0 = smem[0] + 16384;
  const short* As1 = smem[1];
  const short* Bs1 = smem[1] + 16384;

  stage_h(0, 0, 2); stage_h(0, 0, 3); stage_h(0, 0, 0); stage_h(0, 0, 1);
  stage_h(1, 1, 2); stage_h(1, 1, 0);
  VMCNT4();
  BARRIER();

  for (int i = 0; i < NITER; i++) {
    const int t1 = 2 * i + 1;
    const bool more = (i + 1) < NITER;

    READ_AF(As0, 0); READ_BF(Bs0, 0, bf0);
    stage_h(t1, 1, 3);
    BARRIER(); LGKMCNT0(); SCHEDB();
    MFMA_Q(0, 0, bf0);
    BARRIER();
    READ_BF(Bs0, 1, bf1);
    stage_h(t1, 1, 1);
    BARRIER(); LGKMCNT0(); SCHEDB();
    MFMA_Q(0, 1, bf1);
    BARRIER();
    READ_AF(As0, 1);
    if (more) stage_h(t1 + 1, 0, 2);
    BARRIER(); LGKMCNT0(); SCHEDB();
    MFMA_Q(1, 1, bf1);
    BARRIER();
    if (more) { stage_h(t1 + 1, 0, 0); VMCNT4(); } else { VMCNT0(); }
    BARRIER();
    MFMA_Q(1, 0, bf0);
    BARRIER();
    READ_AF(As1, 0); READ_BF(Bs1, 0, bf0);
    if (more) stage_h(t1 + 1, 0, 3);
    BARRIER(); LGKMCNT0(); SCHEDB();
    MFMA_Q(0, 0, bf0);
    BARRIER();
    READ_BF(Bs1, 1, bf1);
    if (more) stage_h(t1 + 1, 0, 1);
    BARRIER(); LGKMCNT0(); SCHEDB();
    MFMA_Q(0, 1, bf1);
    BARRIER();
    READ_AF(As1, 1);
    if (more) stage_h(t1 + 2, 1, 2);
    BARRIER(); LGKMCNT0(); SCHEDB();
    MFMA_Q(1, 1, bf1);
    BARRIER();
    if (more) { stage_h(t1 + 2, 1, 0); VMCNT4(); } else { VMCNT0(); }
    BARRIER();
    MFMA_Q(1, 0, bf0);
    BARRIER();
  }

  // epilogue: P = exp(scale*acc), bf16 store + rowsum PARTIALS (no atomics).
  // Wave (wm,wn) sums its 64-col stripe per row; LDS-reduce across wn; one
  // non-atomic store per (bx,row). Main-loop LDS is dead (drained) -> reuse.
  constexpr float scale = 0.03125f;
  float* sredf = reinterpret_cast<float*>(&smem[0][0]);   // 4 x 256 floats
  #pragma unroll
  for (int i = 0; i < 8; i++) {
    const int r0 = row0 + wm * 128 + i * 16 + quad * 4;
    float ex[4][4];
    #pragma unroll
    for (int j = 0; j < 4; j++) {
      const int c = col0 + wn * 64 + j * 16 + lr;
      #pragma unroll
      for (int r = 0; r < 4; r++) {
        ex[j][r] = __expf(acc[i][j][r] * scale);
        SP[(size_t)(r0 + r) * N_TOK + c] = f2b(ex[j][r]);
      }
    }
    #pragma unroll
    for (int r = 0; r < 4; r++) {
      float s = 0.f;
      #pragma unroll
      for (int j = 0; j < 4; j++) s += ex[j][r];
      s += __shfl_xor(s, 1, 64);
      s += __shfl_xor(s, 2, 64);
      s += __shfl_xor(s, 4, 64);
      s += __shfl_xor(s, 8, 64);
      if (lr == 0)
        sredf[wn * 256 + wm * 128 + i * 16 + quad * 4 + r] = s;
    }
  }
  __syncthreads();
  if (tid < 256) {
    float s = sredf[tid] + sredf[256 + tid] + sredf[512 + tid] + sredf[768 + tid];
    rowsum_p[(size_t)bx * N_TOK + row0 + tid] = s;
  }
}

// ---------------------------------------------------------------------------
// R17 k_pv: 128x64 tile, BK=64, counted-vmcnt double-buffer (R16 schedule).
// R22: rowsum from 16 partials (float4 loads), no atomic dependency.
// ---------------------------------------------------------------------------
__global__ __launch_bounds__(256, 2)
void k_pv(const short* __restrict__ SP, const short* __restrict__ Vt,
          float* __restrict__ out, const float* __restrict__ rowsum_p)
{
  constexpr int BM = 128, BN = 64, BK = 64;
  constexpr int NT = N_TOK / BK;                // 64 K-tiles
  __shared__ short smem[2][(BM + BN) * BK];     // 2 x 12288 shorts = 48 KiB

  int bx = blockIdx.x, by = blockIdx.y;
  xcd_remap(DDIM / 64, bx, by);
  const int row0 = by * BM, col0 = bx * BN;

  const int tid  = threadIdx.x;
  const int wave = tid >> 6, lane = tid & 63;
  const int wm = wave >> 1, wn = wave & 1;      // 2x2 waves, 64x32 out each
  const int quad = lane >> 4, lr = lane & 15;

  auto stage = [&](int t, int sl) {
    #pragma unroll
    for (int c = 0; c < 6; c++) {
      const int id = c * 256 + tid;             // 0..1535
      const int r  = id >> 3;                   // rows 0..191 (A:0-127, B:128-191)
      const int q  = (id & 7) ^ (r & 7);
      const short* src = (r < BM)
          ? SP + (size_t)(row0 + r) * N_TOK + t * BK + q * 8
          : Vt + (size_t)(col0 + r - BM) * N_TOK + t * BK + q * 8;
      gld_lds16(src, &smem[sl][(c * 256 + wave * 64) * 8]);
    }
  };

  f32x4 acc[4][2];
  #pragma unroll
  for (int i = 0; i < 4; i++)
    #pragma unroll
    for (int j = 0; j < 2; j++) acc[i][j] = {0.f, 0.f, 0.f, 0.f};

  stage(0, 0);
  stage(1, 1);
  VMCNT6();
  BARRIER();

  for (int t = 0; t < NT; t++) {
    const int sl = t & 1;
    const short* As = smem[sl];
    const short* Bs = smem[sl] + BM * BK;

    s16x8 af[2][4], bf[2][2];
    #pragma unroll
    for (int h = 0; h < 2; h++) {
      #pragma unroll
      for (int i = 0; i < 4; i++) {
        const int row = wm * 64 + i * 16 + lr;
        const int ch = (h * 4 + quad) ^ (row & 7);
        af[h][i] = *reinterpret_cast<const s16x8*>(&As[(row * 8 + ch) * 8]);
      }
      #pragma unroll
      for (int j = 0; j < 2; j++) {
        const int row = wn * 32 + j * 16 + lr;
        const int ch = (h * 4 + quad) ^ (row & 7);
        bf[h][j] = *reinterpret_cast<const s16x8*>(&Bs[(row * 8 + ch) * 8]);
      }
    }
    LGKMCNT0();
    SCHEDB();
    BARRIER();                                   // slot sl reusable block-wide

    const bool pf = (t + 2) < NT;
    if (pf) stage(t + 2, sl);

    __builtin_amdgcn_s_setprio(1);
    #pragma unroll
    for (int h = 0; h < 2; h++)
      #pragma unroll
      for (int i = 0; i < 4; i++)
        #pragma unroll
        for (int j = 0; j < 2; j++)
          acc[i][j] = __builtin_amdgcn_mfma_f32_16x16x32_bf16(
              af[h][i], bf[h][j], acc[i][j], 0, 0, 0);
    __builtin_amdgcn_s_setprio(0);

    if (pf) { VMCNT6(); } else { VMCNT0(); }
    BARRIER();
  }

  // epilogue: O = acc / rowsum[row]; rowsum = sum of 16 partials (float4).
  #pragma unroll
  for (int i = 0; i < 4; i++) {
    const int r0 = row0 + wm * 64 + i * 16 + quad * 4;
    float4 rsv = {0.f, 0.f, 0.f, 0.f};
    #pragma unroll
    for (int p = 0; p < 16; p++) {
      float4 v = *reinterpret_cast<const float4*>(&rowsum_p[(size_t)p * N_TOK + r0]);
      rsv.x += v.x; rsv.y += v.y; rsv.z += v.z; rsv.w += v.w;
    }
    float linv[4] = {1.0f / rsv.x, 1.0f / rsv.y, 1.0f / rsv.z, 1.0f / rsv.w};
    #pragma unroll
    for (int j = 0; j < 2; j++) {
      const int c = col0 + wn * 32 + j * 16 + lr;
      #pragma unroll
      for (int r = 0; r < 4; r++)
        out[(size_t)(r0 + r) * DDIM + c] = acc[i][j][r] * linv[r];
    }
  }
}

// ---------------------------------------------------------------------------
extern "C" void kernel_launch(void* const* d_in, const int* in_sizes, int n_in,
                              void* d_out, int out_size, void* d_ws, size_t ws_size,
                              hipStream_t stream)
{
  const float* x  = (const float*)d_in[0];
  const float* Wq = (const float*)d_in[1];
  const float* bq = (const float*)d_in[2];
  const float* Wk = (const float*)d_in[3];
  const float* bk = (const float*)d_in[4];
  const float* Wv = (const float*)d_in[5];
  const float* bv = (const float*)d_in[6];
  float* out = (float*)d_out;

  char* ws = (char*)d_ws;
  const size_t MB = 1024 * 1024;
  short* Qb  = (short*)(ws + 0 * MB);
  short* Kb  = (short*)(ws + 8 * MB);
  short* Vt  = (short*)(ws + 24 * MB);
  short* SP  = (short*)(ws + 32 * MB);   // 32 MB (32..64MB)
  short* xb  = (short*)(ws + 32 * MB);   // overlaps SP (dead before k_score)
  short* Wqb = (short*)(ws + 40 * MB);
  short* Wkb = (short*)(ws + 42 * MB);
  short* Wvb = (short*)(ws + 44 * MB);
  float* rowsum_p = (float*)(ws + 64 * MB); // fp32[16][4096], past SP

  dim3 b256(256);

  // fp32 -> bf16 for x and the three W's
  cvt_all<<<dim3(NCVT), b256, 0, stream>>>(
      x, Wq, Wk, Wv, xb, Wqb, Wkb, Wvb);

  // Q/K = x @ W^T + b (bf16); V-slice writes Vt transposed; dbuf-pipelined
  k_qkv<<<dim3(DDIM / 128, N_TOK / 128, 3), b256, 0, stream>>>(
      xb, Wqb, Wkb, Wvb, bq, bk, bv, Qb, Kb, Vt);

  // P = exp(Q @ K^T / 32) (bf16) + rowsum partials; 8-phase 256x256 schedule
  k_score<<<dim3(16, 16), dim3(512), 0, stream>>>(Qb, Kb, SP, rowsum_p);

  // O = (P @ Vt^T) / rowsum (fp32 out), dbuf-pipelined 128x64 BK=64
  k_pv<<<dim3(DDIM / 64, N_TOK / 128), b256, 0, stream>>>(
      SP, Vt, out, rowsum_p);
}